// Round 1
// baseline (136.205 us; speedup 1.0000x reference)
//
#include <hip/hip_runtime.h>
#include <hip/hip_bf16.h>

typedef __attribute__((ext_vector_type(4))) float f32x4;
typedef __attribute__((ext_vector_type(8))) short bf16x8;

#define BM 128
#define BN 128
#define BK 64
#define D_DIM 256
#define MSZ 8192

__device__ __forceinline__ unsigned short f2bf(float f) {
  __hip_bfloat16 h = __float2bfloat16(f);
  unsigned short u; __builtin_memcpy(&u, &h, 2); return u;
}

__global__ __launch_bounds__(256, 2)
void rbf_mfma_kernel(const float* __restrict__ X, const float* __restrict__ Y,
                     float* __restrict__ Out) {
  __shared__ unsigned short As[BM * BK];
  __shared__ unsigned short Bs[BN * BK];
  __shared__ float sx2[BM];
  __shared__ float sy2[BN];

  // XCD-aware swizzle: 4096 blocks, 8 XCDs, 4096 % 8 == 0 -> simple form ok
  int bid = blockIdx.x;
  int cpx = gridDim.x >> 3;
  int swz = (bid & 7) * cpx + (bid >> 3);
  int bm = swz >> 6;   // 64 N-blocks of 128
  int bn = swz & 63;
  int rowBase = bm * BM;
  int colBase = bn * BN;

  int tid = threadIdx.x;
  int l = tid & 63;
  int w = tid >> 6;        // 4 waves: 2x2 sub-tiles of 64x64
  int wr = w >> 1, wc = w & 1;

  f32x4 acc[4][4] = {};
  float assq[4] = {0.f,0.f,0.f,0.f};
  float bssq[4] = {0.f,0.f,0.f,0.f};

  for (int ks = 0; ks < D_DIM / BK; ++ks) {
    if (ks) __syncthreads();
    // ---- stage: 128x64 fp32 -> bf16 LDS for both A and B, fused ssq ----
    #pragma unroll
    for (int p = 0; p < 4; ++p) {
      int c = tid + 256 * p;        // chunk id 0..1023
      int r = c >> 3;               // row 0..127
      int kc = c & 7;               // 8-wide k-chunk
      const float* gx = X + (size_t)(rowBase + r) * D_DIM + ks * BK + kc * 8;
      const float* gy = Y + (size_t)(colBase + r) * D_DIM + ks * BK + kc * 8;
      f32x4 xa = *(const f32x4*)gx;
      f32x4 xb = *(const f32x4*)(gx + 4);
      f32x4 ya = *(const f32x4*)gy;
      f32x4 yb = *(const f32x4*)(gy + 4);
      #pragma unroll
      for (int j = 0; j < 4; ++j) {
        assq[p] += xa[j]*xa[j] + xb[j]*xb[j];
        bssq[p] += ya[j]*ya[j] + yb[j]*yb[j];
      }
      union { bf16x8 v; unsigned short u[8]; } pa, pb;
      #pragma unroll
      for (int j = 0; j < 4; ++j) {
        pa.u[j]   = f2bf(xa[j]);  pa.u[j+4] = f2bf(xb[j]);
        pb.u[j]   = f2bf(ya[j]);  pb.u[j+4] = f2bf(yb[j]);
      }
      // XOR swizzle (G4): keeps ds_read_b128 at 2-way (free)
      int boff = (r * (BK*2) + kc * 16) ^ ((r & 7) << 4);
      *(bf16x8*)((char*)As + boff) = pa.v;
      *(bf16x8*)((char*)Bs + boff) = pb.v;
    }
    __syncthreads();
    // ---- compute: 2 k-slices of 32, 4x4 fragments of 16x16 per wave ----
    #pragma unroll
    for (int kk = 0; kk < 2; ++kk) {
      bf16x8 af[4], bfv[4];
      #pragma unroll
      for (int i = 0; i < 4; ++i) {
        int ra = wr*64 + i*16 + (l & 15);
        int offa = (ra * (BK*2) + kk*64 + (l >> 4) * 16) ^ ((ra & 7) << 4);
        af[i] = *(bf16x8*)((char*)As + offa);
        int rb = wc*64 + i*16 + (l & 15);
        int offb = (rb * (BK*2) + kk*64 + (l >> 4) * 16) ^ ((rb & 7) << 4);
        bfv[i] = *(bf16x8*)((char*)Bs + offb);
      }
      #pragma unroll
      for (int i = 0; i < 4; ++i)
        #pragma unroll
        for (int j = 0; j < 4; ++j)
          acc[i][j] = __builtin_amdgcn_mfma_f32_16x16x32_bf16(af[i], bfv[j], acc[i][j], 0, 0, 0);
    }
  }

  // ---- norm reduction: row r owned by 8 consecutive lanes (t^1,t^2,t^4) ----
  #pragma unroll
  for (int p = 0; p < 4; ++p) {
    float a = assq[p], b = bssq[p];
    a += __shfl_xor(a, 1); b += __shfl_xor(b, 1);
    a += __shfl_xor(a, 2); b += __shfl_xor(b, 2);
    a += __shfl_xor(a, 4); b += __shfl_xor(b, 4);
    if ((tid & 7) == 0) {
      int r = (tid >> 3) + 32 * p;
      sx2[r] = a;
      sy2[r] = b;
    }
  }
  __syncthreads();

  // ---- epilogue: d2 = x2 + y2 - 2*xy, clamp, exp ----
  #pragma unroll
  for (int i = 0; i < 4; ++i) {
    #pragma unroll
    for (int j = 0; j < 4; ++j) {
      #pragma unroll
      for (int q = 0; q < 4; ++q) {
        int rn = wr*64 + i*16 + (l >> 4) * 4 + q;   // C/D: row=(lane>>4)*4+reg
        int cm = wc*64 + j*16 + (l & 15);            //      col=lane&15
        float d2 = sx2[rn] + sy2[cm] - 2.0f * acc[i][j][q];
        d2 = fmaxf(d2, 0.0f);
        Out[(size_t)(rowBase + rn) * MSZ + (colBase + cm)] = __expf(-d2);
      }
    }
  }
}

extern "C" void kernel_launch(void* const* d_in, const int* in_sizes, int n_in,
                              void* d_out, int out_size, void* d_ws, size_t ws_size,
                              hipStream_t stream) {
  const float* X = (const float*)d_in[0];
  const float* Y = (const float*)d_in[1];
  float* Out = (float*)d_out;
  dim3 grid(64 * 64);
  dim3 block(256);
  rbf_mfma_kernel<<<grid, block, 0, stream>>>(X, Y, Out);
}

// Round 2
// 94.864 us; speedup vs baseline: 1.4358x; 1.4358x over previous
//
#include <hip/hip_runtime.h>
#include <hip/hip_bf16.h>

typedef __attribute__((ext_vector_type(4))) float f32x4;
typedef __attribute__((ext_vector_type(8))) short bf16x8;

#define MSZ 8192
#define D_DIM 256
#define BM 128
#define BN 128
#define BK 64

#define GLOAD_LDS(g, s) __builtin_amdgcn_global_load_lds( \
    (const __attribute__((address_space(1))) unsigned int*)(g), \
    (__attribute__((address_space(3))) unsigned int*)(s), 16, 0, 0)

__device__ __forceinline__ unsigned short f2bf(float f) {
  __hip_bfloat16 h = __float2bfloat16(f);
  unsigned short u; __builtin_memcpy(&u, &h, 2); return u;
}

// ---------------- pass 1: fp32 -> bf16 copies + row norms into d_ws ----------------
__global__ __launch_bounds__(256)
void prep_kernel(const float* __restrict__ X, const float* __restrict__ Y,
                 unsigned short* __restrict__ Xb, unsigned short* __restrict__ Yb,
                 float* __restrict__ x2, float* __restrict__ y2) {
  int gw = (blockIdx.x * 256 + threadIdx.x) >> 6;   // one wave per row
  int l = threadIdx.x & 63;
  if (gw >= 2 * MSZ) return;
  int row = gw & (MSZ - 1);
  const float* src = (gw < MSZ ? X : Y) + (size_t)row * D_DIM + l * 4;
  f32x4 v = *(const f32x4*)src;
  float ss = v[0]*v[0] + v[1]*v[1] + v[2]*v[2] + v[3]*v[3];
  ushort4 o;
  o.x = f2bf(v[0]); o.y = f2bf(v[1]); o.z = f2bf(v[2]); o.w = f2bf(v[3]);
  unsigned short* dst = (gw < MSZ ? Xb : Yb) + (size_t)row * D_DIM + l * 4;
  *(ushort4*)dst = o;
  #pragma unroll
  for (int m = 1; m < 64; m <<= 1) ss += __shfl_xor(ss, m);
  if (l == 0) (gw < MSZ ? x2 : y2)[row] = ss;
}

// ---------------- pass 2: bf16 MFMA GEMM + fused exp epilogue ----------------
__global__ __launch_bounds__(256, 4)
void rbf_main(const unsigned short* __restrict__ Xb, const unsigned short* __restrict__ Yb,
              const float* __restrict__ X2, const float* __restrict__ Y2,
              float* __restrict__ Out) {
  // 33792 B region: main loop = As(16K)+Bs(16K) bf16 tiles; epilogue = 64x132 fp32
  __shared__ __align__(16) unsigned char smem[64 * 132 * 4];
  __shared__ float sx2[BM];
  __shared__ float sy2[BN];
  unsigned char* As = smem;
  unsigned char* Bs = smem + 16384;

  int bid = blockIdx.x;
  int cpx = gridDim.x >> 3;             // 4096 % 8 == 0 -> simple bijective swizzle
  int swz = (bid & 7) * cpx + (bid >> 3);
  int bm = swz >> 6;
  int bn = swz & 63;
  int rowBase = bm * BM, colBase = bn * BN;

  int tid = threadIdx.x;
  int l = tid & 63;
  int w = tid >> 6;          // 4 waves, 2x2 grid of 64x64 output sub-tiles
  int wr = w >> 1, wc = w & 1;

  if (tid < 128) sx2[tid] = X2[rowBase + tid];
  else           sy2[tid - 128] = Y2[colBase + tid - 128];

  f32x4 acc[4][4] = {};

  for (int ks = 0; ks < D_DIM / BK; ++ks) {
    if (ks) __syncthreads();
    // stage: wave w DMAs rows [w*32, w*32+32) of A and B, 8 rows (1 KB) per inst.
    // LDS dest linear; XOR swizzle applied on the GLOBAL source column (m173 pattern)
    #pragma unroll
    for (int q = 0; q < 4; ++q) {
      int row = w * 32 + q * 8 + (l >> 3);
      int gcol = ks * BK + (((l & 7) ^ (row & 7)) << 3);
      const unsigned short* ga = Xb + (size_t)(rowBase + row) * D_DIM + gcol;
      const unsigned short* gb = Yb + (size_t)(colBase + row) * D_DIM + gcol;
      GLOAD_LDS(ga, As + (w * 32 + q * 8) * 128);
      GLOAD_LDS(gb, Bs + (w * 32 + q * 8) * 128);
    }
    asm volatile("s_waitcnt vmcnt(0)" ::: "memory");
    __syncthreads();
    // compute: 2 k-slices of 32, 4x4 fragments of 16x16 per wave
    #pragma unroll
    for (int kk = 0; kk < 2; ++kk) {
      bf16x8 af[4], bfv[4];
      #pragma unroll
      for (int i = 0; i < 4; ++i) {
        int ra = wr * 64 + i * 16 + (l & 15);
        int offa = (ra * 128 + kk * 64 + (l >> 4) * 16) ^ ((ra & 7) << 4);
        af[i] = *(bf16x8*)(As + offa);
        int rb = wc * 64 + i * 16 + (l & 15);
        int offb = (rb * 128 + kk * 64 + (l >> 4) * 16) ^ ((rb & 7) << 4);
        bfv[i] = *(bf16x8*)(Bs + offb);
      }
      #pragma unroll
      for (int i = 0; i < 4; ++i)
        #pragma unroll
        for (int j = 0; j < 4; ++j)
          acc[i][j] = __builtin_amdgcn_mfma_f32_16x16x32_bf16(af[i], bfv[j], acc[i][j], 0, 0, 0);
    }
  }

  // ---- epilogue: exp(-(x2+y2-2xy)) staged through LDS, then full-line f32x4 stores ----
  __syncthreads();                       // all LDS tile reads done before reuse
  float* epi = (float*)smem;             // [64][132] fp32, pad keeps frag writes 2-way max
  #pragma unroll
  for (int h = 0; h < 2; ++h) {
    if (h) __syncthreads();              // pass-0 readback done before overwrite
    if (wr == h) {
      #pragma unroll
      for (int i = 0; i < 4; ++i)
        #pragma unroll
        for (int j = 0; j < 4; ++j)
          #pragma unroll
          for (int q = 0; q < 4; ++q) {
            int rr = i * 16 + (l >> 4) * 4 + q;    // C/D: row=(lane>>4)*4+reg
            int cm = wc * 64 + j * 16 + (l & 15);  //      col=lane&15
            float d2 = sx2[h * 64 + rr] + sy2[cm] - 2.0f * acc[i][j][q];
            epi[rr * 132 + cm] = __expf(-fmaxf(d2, 0.0f));
          }
    }
    __syncthreads();
    // stream out 64x128 fp32: 32 lanes cover a full 512B row -> full lines, no RFO
    #pragma unroll
    for (int p = 0; p < 8; ++p) {
      int f = tid + 256 * p;
      int rr = f >> 5, c4 = f & 31;
      f32x4 v = *(const f32x4*)(epi + rr * 132 + c4 * 4);
      *(f32x4*)(Out + (size_t)(rowBase + h * 64 + rr) * MSZ + colBase + c4 * 4) = v;
    }
  }
}

// ---------------- fallback (round-1 kernel, used only if ws too small) ----------------
__global__ __launch_bounds__(256, 2)
void rbf_mfma_kernel(const float* __restrict__ X, const float* __restrict__ Y,
                     float* __restrict__ Out) {
  __shared__ unsigned short As[BM * BK];
  __shared__ unsigned short Bs[BN * BK];
  __shared__ float sx2[BM];
  __shared__ float sy2[BN];
  int bid = blockIdx.x;
  int cpx = gridDim.x >> 3;
  int swz = (bid & 7) * cpx + (bid >> 3);
  int bm = swz >> 6, bn = swz & 63;
  int rowBase = bm * BM, colBase = bn * BN;
  int tid = threadIdx.x;
  int l = tid & 63;
  int w = tid >> 6;
  int wr = w >> 1, wc = w & 1;
  f32x4 acc[4][4] = {};
  float assq[4] = {0.f,0.f,0.f,0.f};
  float bssq[4] = {0.f,0.f,0.f,0.f};
  for (int ks = 0; ks < D_DIM / BK; ++ks) {
    if (ks) __syncthreads();
    #pragma unroll
    for (int p = 0; p < 4; ++p) {
      int c = tid + 256 * p;
      int r = c >> 3;
      int kc = c & 7;
      const float* gx = X + (size_t)(rowBase + r) * D_DIM + ks * BK + kc * 8;
      const float* gy = Y + (size_t)(colBase + r) * D_DIM + ks * BK + kc * 8;
      f32x4 xa = *(const f32x4*)gx;
      f32x4 xb = *(const f32x4*)(gx + 4);
      f32x4 ya = *(const f32x4*)gy;
      f32x4 yb = *(const f32x4*)(gy + 4);
      #pragma unroll
      for (int j = 0; j < 4; ++j) {
        assq[p] += xa[j]*xa[j] + xb[j]*xb[j];
        bssq[p] += ya[j]*ya[j] + yb[j]*yb[j];
      }
      union { bf16x8 v; unsigned short u[8]; } pa, pb;
      #pragma unroll
      for (int j = 0; j < 4; ++j) {
        pa.u[j] = f2bf(xa[j]);  pa.u[j+4] = f2bf(xb[j]);
        pb.u[j] = f2bf(ya[j]);  pb.u[j+4] = f2bf(yb[j]);
      }
      int boff = (r * (BK*2) + kc * 16) ^ ((r & 7) << 4);
      *(bf16x8*)((char*)As + boff) = pa.v;
      *(bf16x8*)((char*)Bs + boff) = pb.v;
    }
    __syncthreads();
    #pragma unroll
    for (int kk = 0; kk < 2; ++kk) {
      bf16x8 af[4], bfv[4];
      #pragma unroll
      for (int i = 0; i < 4; ++i) {
        int ra = wr*64 + i*16 + (l & 15);
        int offa = (ra * (BK*2) + kk*64 + (l >> 4) * 16) ^ ((ra & 7) << 4);
        af[i] = *(bf16x8*)((char*)As + offa);
        int rb = wc*64 + i*16 + (l & 15);
        int offb = (rb * (BK*2) + kk*64 + (l >> 4) * 16) ^ ((rb & 7) << 4);
        bfv[i] = *(bf16x8*)((char*)Bs + offb);
      }
      #pragma unroll
      for (int i = 0; i < 4; ++i)
        #pragma unroll
        for (int j = 0; j < 4; ++j)
          acc[i][j] = __builtin_amdgcn_mfma_f32_16x16x32_bf16(af[i], bfv[j], acc[i][j], 0, 0, 0);
    }
  }
  #pragma unroll
  for (int p = 0; p < 4; ++p) {
    float a = assq[p], b = bssq[p];
    a += __shfl_xor(a, 1); b += __shfl_xor(b, 1);
    a += __shfl_xor(a, 2); b += __shfl_xor(b, 2);
    a += __shfl_xor(a, 4); b += __shfl_xor(b, 4);
    if ((tid & 7) == 0) {
      int r = (tid >> 3) + 32 * p;
      sx2[r] = a;
      sy2[r] = b;
    }
  }
  __syncthreads();
  #pragma unroll
  for (int i = 0; i < 4; ++i)
    #pragma unroll
    for (int j = 0; j < 4; ++j)
      #pragma unroll
      for (int q = 0; q < 4; ++q) {
        int rn = wr*64 + i*16 + (l >> 4) * 4 + q;
        int cm = wc*64 + j*16 + (l & 15);
        float d2 = sx2[rn] + sy2[cm] - 2.0f * acc[i][j][q];
        Out[(size_t)(rowBase + rn) * MSZ + (colBase + cm)] = __expf(-fmaxf(d2, 0.0f));
      }
}

extern "C" void kernel_launch(void* const* d_in, const int* in_sizes, int n_in,
                              void* d_out, int out_size, void* d_ws, size_t ws_size,
                              hipStream_t stream) {
  const float* X = (const float*)d_in[0];
  const float* Y = (const float*)d_in[1];
  float* Out = (float*)d_out;
  const size_t NEED = (size_t)MSZ * D_DIM * 2 * 2 + (size_t)MSZ * 4 * 2;  // Xb+Yb+x2+y2
  if (ws_size >= NEED) {
    unsigned short* Xb = (unsigned short*)d_ws;
    unsigned short* Yb = Xb + (size_t)MSZ * D_DIM;
    float* x2 = (float*)(Yb + (size_t)MSZ * D_DIM);
    float* y2 = x2 + MSZ;
    prep_kernel<<<dim3(4096), dim3(256), 0, stream>>>(X, Y, Xb, Yb, x2, y2);
    rbf_main<<<dim3(64 * 64), dim3(256), 0, stream>>>(Xb, Yb, x2, y2, Out);
  } else {
    rbf_mfma_kernel<<<dim3(64 * 64), dim3(256), 0, stream>>>(X, Y, Out);
  }
}

// Round 3
// 89.744 us; speedup vs baseline: 1.5177x; 1.0570x over previous
//
#include <hip/hip_runtime.h>
#include <hip/hip_bf16.h>

typedef __attribute__((ext_vector_type(4))) float f32x4;
typedef __attribute__((ext_vector_type(8))) short bf16x8;
typedef __attribute__((ext_vector_type(16))) float f32x16;

#define MSZ 8192
#define D_DIM 256
#define BM 128
#define BN 128
#define BK 64
#define NT (D_DIM / BK)   // 4 K-tiles

#define GLOAD_LDS(g, s) __builtin_amdgcn_global_load_lds( \
    (const __attribute__((address_space(1))) unsigned int*)(g), \
    (__attribute__((address_space(3))) unsigned int*)(s), 16, 0, 0)

__device__ __forceinline__ unsigned short f2bf(float f) {
  __hip_bfloat16 h = __float2bfloat16(f);
  unsigned short u; __builtin_memcpy(&u, &h, 2); return u;
}

// ---------------- pass 1: fp32 -> bf16 copies + row norms into d_ws ----------------
__global__ __launch_bounds__(256)
void prep_kernel(const float* __restrict__ X, const float* __restrict__ Y,
                 unsigned short* __restrict__ Xb, unsigned short* __restrict__ Yb,
                 float* __restrict__ x2, float* __restrict__ y2) {
  int gw = (blockIdx.x * 256 + threadIdx.x) >> 6;   // one wave per row
  int l = threadIdx.x & 63;
  if (gw >= 2 * MSZ) return;
  int row = gw & (MSZ - 1);
  const float* src = (gw < MSZ ? X : Y) + (size_t)row * D_DIM + l * 4;
  f32x4 v = *(const f32x4*)src;
  float ss = v[0]*v[0] + v[1]*v[1] + v[2]*v[2] + v[3]*v[3];
  ushort4 o;
  o.x = f2bf(v[0]); o.y = f2bf(v[1]); o.z = f2bf(v[2]); o.w = f2bf(v[3]);
  unsigned short* dst = (gw < MSZ ? Xb : Yb) + (size_t)row * D_DIM + l * 4;
  *(ushort4*)dst = o;
  #pragma unroll
  for (int m = 1; m < 64; m <<= 1) ss += __shfl_xor(ss, m);
  if (l == 0) (gw < MSZ ? x2 : y2)[row] = ss;
}

// ---------------- pass 2: dbuf bf16 MFMA (32x32) + direct full-line stores ----------------
__global__ __launch_bounds__(256, 2)
void rbf_main(const unsigned short* __restrict__ Xb, const unsigned short* __restrict__ Yb,
              const float* __restrict__ X2, const float* __restrict__ Y2,
              float* __restrict__ Out) {
  __shared__ __align__(16) unsigned char smem[4 * 16384];   // dbuf A(16K)+B(16K)
  __shared__ float sx2[BM];

  int bid = blockIdx.x;
  int cpx = gridDim.x >> 3;             // 4096 % 8 == 0 -> bijective XCD swizzle
  int swz = (bid & 7) * cpx + (bid >> 3);
  int bm = swz >> 6;
  int bn = swz & 63;
  int rowBase = bm * BM, colBase = bn * BN;

  int tid = threadIdx.x;
  int l = tid & 63;
  int w = tid >> 6;          // 4 waves, 2x2 grid of 64x64 output sub-tiles
  int wr = w >> 1, wc = w & 1;

  if (tid < BM) sx2[tid] = X2[rowBase + tid];
  float sy0 = Y2[colBase + wc * 64 + (l & 31)];
  float sy1 = Y2[colBase + wc * 64 + 32 + (l & 31)];

  f32x16 acc[2][2] = {};

  #define STAGE(t, Abuf, Bbuf)                                                     \
    _Pragma("unroll")                                                              \
    for (int q = 0; q < 4; ++q) {                                                  \
      int row = w * 32 + q * 8 + (l >> 3);                                         \
      int gcol = (t) * BK + (((l & 7) ^ (row & 7)) << 3);                          \
      GLOAD_LDS(Xb + (size_t)(rowBase + row) * D_DIM + gcol, (Abuf) + (w*32 + q*8) * 128); \
      GLOAD_LDS(Yb + (size_t)(colBase + row) * D_DIM + gcol, (Bbuf) + (w*32 + q*8) * 128); \
    }

  #define COMPUTE(Abuf, Bbuf)                                                      \
    _Pragma("unroll")                                                              \
    for (int kk = 0; kk < 4; ++kk) {                                               \
      bf16x8 af[2], bfv[2];                                                        \
      _Pragma("unroll")                                                            \
      for (int i = 0; i < 2; ++i) {                                                \
        int ra = wr * 64 + i * 32 + (l & 31);                                      \
        int offa = ra * 128 + (((kk * 2 + (l >> 5)) << 4) ^ ((ra & 7) << 4));      \
        af[i] = *(bf16x8*)((Abuf) + offa);                                         \
        int rb = wc * 64 + i * 32 + (l & 31);                                      \
        int offb = rb * 128 + (((kk * 2 + (l >> 5)) << 4) ^ ((rb & 7) << 4));      \
        bfv[i] = *(bf16x8*)((Bbuf) + offb);                                        \
      }                                                                            \
      _Pragma("unroll")                                                            \
      for (int i = 0; i < 2; ++i)                                                  \
        _Pragma("unroll")                                                          \
        for (int j = 0; j < 2; ++j)                                                \
          acc[i][j] = __builtin_amdgcn_mfma_f32_32x32x16_bf16(af[i], bfv[j], acc[i][j], 0, 0, 0); \
    }

  unsigned char* A0 = smem;
  unsigned char* B0 = smem + 16384;
  unsigned char* A1 = smem + 32768;
  unsigned char* B1 = smem + 49152;

  STAGE(0, A0, B0)
  #pragma unroll
  for (int t = 0; t < NT; ++t) {
    __syncthreads();                       // tile t staged & visible to all waves
    unsigned char* Ac = (t & 1) ? A1 : A0;
    unsigned char* Bc = (t & 1) ? B1 : B0;
    if (t + 1 < NT) {
      unsigned char* An = (t & 1) ? A0 : A1;
      unsigned char* Bn = (t & 1) ? B0 : B1;
      STAGE(t + 1, An, Bn)
    }
    COMPUTE(Ac, Bc)
  }

  // ---- epilogue: direct stores from 32x32 accumulators (full 128B lines) ----
  // C/D layout: col = l&31, row = (q&3) + 8*(q>>2) + 4*(l>>5)   [m74/m101]
  #pragma unroll
  for (int i = 0; i < 2; ++i) {
    int rb0 = wr * 64 + i * 32 + ((l >> 5) << 2);
    float* base = Out + (size_t)(rowBase + rb0) * MSZ + colBase + wc * 64 + (l & 31);
    #pragma unroll
    for (int q = 0; q < 16; ++q) {
      int rpat = (q & 3) + 8 * (q >> 2);
      float sx = sx2[rb0 + rpat];          // LDS broadcast (uniform per half-wave)
      float d0 = fmaf(-2.0f, acc[i][0][q], sx + sy0);
      float d1 = fmaf(-2.0f, acc[i][1][q], sx + sy1);
      base[(size_t)rpat * MSZ]      = __expf(-fmaxf(d0, 0.0f));
      base[(size_t)rpat * MSZ + 32] = __expf(-fmaxf(d1, 0.0f));
    }
  }
  #undef STAGE
  #undef COMPUTE
}

// ---------------- fallback (round-1 kernel, used only if ws too small) ----------------
__global__ __launch_bounds__(256, 2)
void rbf_mfma_kernel(const float* __restrict__ X, const float* __restrict__ Y,
                     float* __restrict__ Out) {
  __shared__ unsigned short As[BM * BK];
  __shared__ unsigned short Bs[BN * BK];
  __shared__ float sx2[BM];
  __shared__ float sy2[BN];
  int bid = blockIdx.x;
  int cpx = gridDim.x >> 3;
  int swz = (bid & 7) * cpx + (bid >> 3);
  int bm = swz >> 6, bn = swz & 63;
  int rowBase = bm * BM, colBase = bn * BN;
  int tid = threadIdx.x;
  int l = tid & 63;
  int w = tid >> 6;
  int wr = w >> 1, wc = w & 1;
  f32x4 acc[4][4] = {};
  float assq[4] = {0.f,0.f,0.f,0.f};
  float bssq[4] = {0.f,0.f,0.f,0.f};
  for (int ks = 0; ks < D_DIM / BK; ++ks) {
    if (ks) __syncthreads();
    #pragma unroll
    for (int p = 0; p < 4; ++p) {
      int c = tid + 256 * p;
      int r = c >> 3;
      int kc = c & 7;
      const float* gx = X + (size_t)(rowBase + r) * D_DIM + ks * BK + kc * 8;
      const float* gy = Y + (size_t)(colBase + r) * D_DIM + ks * BK + kc * 8;
      f32x4 xa = *(const f32x4*)gx;
      f32x4 xb = *(const f32x4*)(gx + 4);
      f32x4 ya = *(const f32x4*)gy;
      f32x4 yb = *(const f32x4*)(gy + 4);
      #pragma unroll
      for (int j = 0; j < 4; ++j) {
        assq[p] += xa[j]*xa[j] + xb[j]*xb[j];
        bssq[p] += ya[j]*ya[j] + yb[j]*yb[j];
      }
      union { bf16x8 v; unsigned short u[8]; } pa, pb;
      #pragma unroll
      for (int j = 0; j < 4; ++j) {
        pa.u[j] = f2bf(xa[j]);  pa.u[j+4] = f2bf(xb[j]);
        pb.u[j] = f2bf(ya[j]);  pb.u[j+4] = f2bf(yb[j]);
      }
      int boff = (r * (BK*2) + kc * 16) ^ ((r & 7) << 4);
      *(bf16x8*)((char*)As + boff) = pa.v;
      *(bf16x8*)((char*)Bs + boff) = pb.v;
    }
    __syncthreads();
    #pragma unroll
    for (int kk = 0; kk < 2; ++kk) {
      bf16x8 af[4], bfv[4];
      #pragma unroll
      for (int i = 0; i < 4; ++i) {
        int ra = wr*64 + i*16 + (l & 15);
        int offa = (ra * (BK*2) + kk*64 + (l >> 4) * 16) ^ ((ra & 7) << 4);
        af[i] = *(bf16x8*)((char*)As + offa);
        int rb = wc*64 + i*16 + (l & 15);
        int offb = (rb * (BK*2) + kk*64 + (l >> 4) * 16) ^ ((rb & 7) << 4);
        bfv[i] = *(bf16x8*)((char*)Bs + offb);
      }
      #pragma unroll
      for (int i = 0; i < 4; ++i)
        #pragma unroll
        for (int j = 0; j < 4; ++j)
          acc[i][j] = __builtin_amdgcn_mfma_f32_16x16x32_bf16(af[i], bfv[j], acc[i][j], 0, 0, 0);
    }
  }
  #pragma unroll
  for (int p = 0; p < 4; ++p) {
    float a = assq[p], b = bssq[p];
    a += __shfl_xor(a, 1); b += __shfl_xor(b, 1);
    a += __shfl_xor(a, 2); b += __shfl_xor(b, 2);
    a += __shfl_xor(a, 4); b += __shfl_xor(b, 4);
    if ((tid & 7) == 0) {
      int r = (tid >> 3) + 32 * p;
      sx2[r] = a;
      sy2[r] = b;
    }
  }
  __syncthreads();
  #pragma unroll
  for (int i = 0; i < 4; ++i)
    #pragma unroll
    for (int j = 0; j < 4; ++j)
      #pragma unroll
      for (int q = 0; q < 4; ++q) {
        int rn = wr*64 + i*16 + (l >> 4) * 4 + q;
        int cm = wc*64 + j*16 + (l & 15);
        float d2 = sx2[rn] + sy2[cm] - 2.0f * acc[i][j][q];
        Out[(size_t)(rowBase + rn) * MSZ + (colBase + cm)] = __expf(-fmaxf(d2, 0.0f));
      }
}

extern "C" void kernel_launch(void* const* d_in, const int* in_sizes, int n_in,
                              void* d_out, int out_size, void* d_ws, size_t ws_size,
                              hipStream_t stream) {
  const float* X = (const float*)d_in[0];
  const float* Y = (const float*)d_in[1];
  float* Out = (float*)d_out;
  const size_t NEED = (size_t)MSZ * D_DIM * 2 * 2 + (size_t)MSZ * 4 * 2;  // Xb+Yb+x2+y2
  if (ws_size >= NEED) {
    unsigned short* Xb = (unsigned short*)d_ws;
    unsigned short* Yb = Xb + (size_t)MSZ * D_DIM;
    float* x2 = (float*)(Yb + (size_t)MSZ * D_DIM);
    float* y2 = x2 + MSZ;
    prep_kernel<<<dim3(4096), dim3(256), 0, stream>>>(X, Y, Xb, Yb, x2, y2);
    rbf_main<<<dim3(64 * 64), dim3(256), 0, stream>>>(Xb, Yb, x2, y2, Out);
  } else {
    rbf_mfma_kernel<<<dim3(64 * 64), dim3(256), 0, stream>>>(X, Y, Out);
  }
}

// Round 4
// 82.491 us; speedup vs baseline: 1.6512x; 1.0879x over previous
//
#include <hip/hip_runtime.h>
#include <hip/hip_bf16.h>

typedef __attribute__((ext_vector_type(4))) float f32x4;
typedef __attribute__((ext_vector_type(8))) short bf16x8;
typedef __attribute__((ext_vector_type(16))) float f32x16;

#define MSZ 8192
#define D_DIM 256
#define BM 128
#define BN 128
#define BK 64
#define NT (D_DIM / BK)   // 4 K-tiles

#define GLOAD_LDS(g, s) __builtin_amdgcn_global_load_lds( \
    (const __attribute__((address_space(1))) unsigned int*)(g), \
    (__attribute__((address_space(3))) unsigned int*)(s), 16, 0, 0)

__device__ __forceinline__ unsigned short f2bf(float f) {
  __hip_bfloat16 h = __float2bfloat16(f);
  unsigned short u; __builtin_memcpy(&u, &h, 2); return u;
}

// ---------------- pass 1: fp32 -> bf16 copies + row norms into d_ws ----------------
__global__ __launch_bounds__(256)
void prep_kernel(const float* __restrict__ X, const float* __restrict__ Y,
                 unsigned short* __restrict__ Xb, unsigned short* __restrict__ Yb,
                 float* __restrict__ x2, float* __restrict__ y2) {
  int gw = (blockIdx.x * 256 + threadIdx.x) >> 6;   // one wave per row
  int l = threadIdx.x & 63;
  if (gw >= 2 * MSZ) return;
  int row = gw & (MSZ - 1);
  const float* src = (gw < MSZ ? X : Y) + (size_t)row * D_DIM + l * 4;
  f32x4 v = *(const f32x4*)src;
  float ss = v[0]*v[0] + v[1]*v[1] + v[2]*v[2] + v[3]*v[3];
  ushort4 o;
  o.x = f2bf(v[0]); o.y = f2bf(v[1]); o.z = f2bf(v[2]); o.w = f2bf(v[3]);
  unsigned short* dst = (gw < MSZ ? Xb : Yb) + (size_t)row * D_DIM + l * 4;
  *(ushort4*)dst = o;
  #pragma unroll
  for (int m = 1; m < 64; m <<= 1) ss += __shfl_xor(ss, m);
  if (l == 0) (gw < MSZ ? x2 : y2)[row] = ss;
}

// ------- pass 2: single-buffer bf16 MFMA (32x32), 4 blocks/CU, direct stores -------
__global__ __launch_bounds__(256, 4)
void rbf_main(const unsigned short* __restrict__ Xb, const unsigned short* __restrict__ Yb,
              const float* __restrict__ X2, const float* __restrict__ Y2,
              float* __restrict__ Out) {
  __shared__ __align__(16) unsigned char smem[2 * 16384];   // A(16K)+B(16K), single buffer
  __shared__ float sx2[BM];

  int bid = blockIdx.x;
  int cpx = gridDim.x >> 3;             // 4096 % 8 == 0 -> bijective XCD swizzle
  int swz = (bid & 7) * cpx + (bid >> 3);
  int bm = swz >> 6;
  int bn = swz & 63;
  int rowBase = bm * BM, colBase = bn * BN;

  int tid = threadIdx.x;
  int l = tid & 63;
  int w = tid >> 6;          // 4 waves, 2x2 grid of 64x64 output sub-tiles
  int wr = w >> 1, wc = w & 1;

  if (tid < BM) sx2[tid] = X2[rowBase + tid];
  float sy0 = Y2[colBase + wc * 64 + (l & 31)];
  float sy1 = Y2[colBase + wc * 64 + 32 + (l & 31)];

  f32x16 acc[2][2] = {};

  unsigned char* As = smem;
  unsigned char* Bs = smem + 16384;

  // stage: wave w DMAs rows [w*32, w*32+32); LDS dest linear (gload_lds reqmt),
  // XOR swizzle applied on the GLOBAL source column (m173 pattern)
  #define STAGE(t)                                                                 \
    _Pragma("unroll")                                                              \
    for (int q = 0; q < 4; ++q) {                                                  \
      int row = w * 32 + q * 8 + (l >> 3);                                         \
      int gcol = (t) * BK + (((l & 7) ^ (row & 7)) << 3);                          \
      GLOAD_LDS(Xb + (size_t)(rowBase + row) * D_DIM + gcol, As + (w*32 + q*8) * 128); \
      GLOAD_LDS(Yb + (size_t)(colBase + row) * D_DIM + gcol, Bs + (w*32 + q*8) * 128); \
    }

  #define COMPUTE()                                                                \
    _Pragma("unroll")                                                              \
    for (int kk = 0; kk < 4; ++kk) {                                               \
      bf16x8 af[2], bfv[2];                                                        \
      _Pragma("unroll")                                                            \
      for (int i = 0; i < 2; ++i) {                                                \
        int ra = wr * 64 + i * 32 + (l & 31);                                      \
        int offa = ra * 128 + (((kk * 2 + (l >> 5)) << 4) ^ ((ra & 7) << 4));      \
        af[i] = *(bf16x8*)(As + offa);                                             \
        int rb = wc * 64 + i * 32 + (l & 31);                                      \
        int offb = rb * 128 + (((kk * 2 + (l >> 5)) << 4) ^ ((rb & 7) << 4));      \
        bfv[i] = *(bf16x8*)(Bs + offb);                                            \
      }                                                                            \
      _Pragma("unroll")                                                            \
      for (int i = 0; i < 2; ++i)                                                  \
        _Pragma("unroll")                                                          \
        for (int j = 0; j < 2; ++j)                                                \
          acc[i][j] = __builtin_amdgcn_mfma_f32_32x32x16_bf16(af[i], bfv[j], acc[i][j], 0, 0, 0); \
    }

  STAGE(0)
  #pragma unroll
  for (int t = 0; t < NT; ++t) {
    __syncthreads();                 // vmcnt(0)+lgkmcnt(0)+barrier: tile t visible
    COMPUTE()
    if (t + 1 < NT) {
      __syncthreads();               // all reads of tile t done before overwrite
      STAGE(t + 1)
    }
  }

  // ---- epilogue: direct stores from 32x32 accumulators (full 128B lines) ----
  // C/D layout: col = l&31, row = (q&3) + 8*(q>>2) + 4*(l>>5)   [m74/m101]
  #pragma unroll
  for (int i = 0; i < 2; ++i) {
    int rb0 = wr * 64 + i * 32 + ((l >> 5) << 2);
    float* base = Out + (size_t)(rowBase + rb0) * MSZ + colBase + wc * 64 + (l & 31);
    #pragma unroll
    for (int q = 0; q < 16; ++q) {
      int rpat = (q & 3) + 8 * (q >> 2);
      float sx = sx2[rb0 + rpat];          // LDS broadcast (uniform per half-wave)
      float d0 = fmaf(-2.0f, acc[i][0][q], sx + sy0);
      float d1 = fmaf(-2.0f, acc[i][1][q], sx + sy1);
      base[(size_t)rpat * MSZ]      = __expf(-fmaxf(d0, 0.0f));
      base[(size_t)rpat * MSZ + 32] = __expf(-fmaxf(d1, 0.0f));
    }
  }
  #undef STAGE
  #undef COMPUTE
}

// ---------------- fallback (round-1 kernel, used only if ws too small) ----------------
__global__ __launch_bounds__(256, 2)
void rbf_mfma_kernel(const float* __restrict__ X, const float* __restrict__ Y,
                     float* __restrict__ Out) {
  __shared__ unsigned short As[BM * BK];
  __shared__ unsigned short Bs[BN * BK];
  __shared__ float sx2[BM];
  __shared__ float sy2[BN];
  int bid = blockIdx.x;
  int cpx = gridDim.x >> 3;
  int swz = (bid & 7) * cpx + (bid >> 3);
  int bm = swz >> 6, bn = swz & 63;
  int rowBase = bm * BM, colBase = bn * BN;
  int tid = threadIdx.x;
  int l = tid & 63;
  int w = tid >> 6;
  int wr = w >> 1, wc = w & 1;
  f32x4 acc[4][4] = {};
  float assq[4] = {0.f,0.f,0.f,0.f};
  float bssq[4] = {0.f,0.f,0.f,0.f};
  for (int ks = 0; ks < D_DIM / BK; ++ks) {
    if (ks) __syncthreads();
    #pragma unroll
    for (int p = 0; p < 4; ++p) {
      int c = tid + 256 * p;
      int r = c >> 3;
      int kc = c & 7;
      const float* gx = X + (size_t)(rowBase + r) * D_DIM + ks * BK + kc * 8;
      const float* gy = Y + (size_t)(colBase + r) * D_DIM + ks * BK + kc * 8;
      f32x4 xa = *(const f32x4*)gx;
      f32x4 xb = *(const f32x4*)(gx + 4);
      f32x4 ya = *(const f32x4*)gy;
      f32x4 yb = *(const f32x4*)(gy + 4);
      #pragma unroll
      for (int j = 0; j < 4; ++j) {
        assq[p] += xa[j]*xa[j] + xb[j]*xb[j];
        bssq[p] += ya[j]*ya[j] + yb[j]*yb[j];
      }
      union { bf16x8 v; unsigned short u[8]; } pa, pb;
      #pragma unroll
      for (int j = 0; j < 4; ++j) {
        pa.u[j] = f2bf(xa[j]);  pa.u[j+4] = f2bf(xb[j]);
        pb.u[j] = f2bf(ya[j]);  pb.u[j+4] = f2bf(yb[j]);
      }
      int boff = (r * (BK*2) + kc * 16) ^ ((r & 7) << 4);
      *(bf16x8*)((char*)As + boff) = pa.v;
      *(bf16x8*)((char*)Bs + boff) = pb.v;
    }
    __syncthreads();
    #pragma unroll
    for (int kk = 0; kk < 2; ++kk) {
      bf16x8 af[4], bfv[4];
      #pragma unroll
      for (int i = 0; i < 4; ++i) {
        int ra = wr*64 + i*16 + (l & 15);
        int offa = (ra * (BK*2) + kk*64 + (l >> 4) * 16) ^ ((ra & 7) << 4);
        af[i] = *(bf16x8*)((char*)As + offa);
        int rb = wc*64 + i*16 + (l & 15);
        int offb = (rb * (BK*2) + kk*64 + (l >> 4) * 16) ^ ((rb & 7) << 4);
        bfv[i] = *(bf16x8*)((char*)Bs + offb);
      }
      #pragma unroll
      for (int i = 0; i < 4; ++i)
        #pragma unroll
        for (int j = 0; j < 4; ++j)
          acc[i][j] = __builtin_amdgcn_mfma_f32_16x16x32_bf16(af[i], bfv[j], acc[i][j], 0, 0, 0);
    }
  }
  #pragma unroll
  for (int p = 0; p < 4; ++p) {
    float a = assq[p], b = bssq[p];
    a += __shfl_xor(a, 1); b += __shfl_xor(b, 1);
    a += __shfl_xor(a, 2); b += __shfl_xor(b, 2);
    a += __shfl_xor(a, 4); b += __shfl_xor(b, 4);
    if ((tid & 7) == 0) {
      int r = (tid >> 3) + 32 * p;
      sx2[r] = a;
      sy2[r] = b;
    }
  }
  __syncthreads();
  #pragma unroll
  for (int i = 0; i < 4; ++i)
    #pragma unroll
    for (int j = 0; j < 4; ++j)
      #pragma unroll
      for (int q = 0; q < 4; ++q) {
        int rn = wr*64 + i*16 + (l >> 4) * 4 + q;
        int cm = wc*64 + j*16 + (l & 15);
        float d2 = sx2[rn] + sy2[cm] - 2.0f * acc[i][j][q];
        Out[(size_t)(rowBase + rn) * MSZ + (colBase + cm)] = __expf(-fmaxf(d2, 0.0f));
      }
}

extern "C" void kernel_launch(void* const* d_in, const int* in_sizes, int n_in,
                              void* d_out, int out_size, void* d_ws, size_t ws_size,
                              hipStream_t stream) {
  const float* X = (const float*)d_in[0];
  const float* Y = (const float*)d_in[1];
  float* Out = (float*)d_out;
  const size_t NEED = (size_t)MSZ * D_DIM * 2 * 2 + (size_t)MSZ * 4 * 2;  // Xb+Yb+x2+y2
  if (ws_size >= NEED) {
    unsigned short* Xb = (unsigned short*)d_ws;
    unsigned short* Yb = Xb + (size_t)MSZ * D_DIM;
    float* x2 = (float*)(Yb + (size_t)MSZ * D_DIM);
    float* y2 = x2 + MSZ;
    prep_kernel<<<dim3(4096), dim3(256), 0, stream>>>(X, Y, Xb, Yb, x2, y2);
    rbf_main<<<dim3(64 * 64), dim3(256), 0, stream>>>(Xb, Yb, x2, y2, Out);
  } else {
    rbf_mfma_kernel<<<dim3(64 * 64), dim3(256), 0, stream>>>(X, Y, Out);
  }
}